// Round 7
// baseline (649.982 us; speedup 1.0000x reference)
//
#include <hip/hip_runtime.h>

#define NQ 1024
#define NO 2048
#define LAT 128
#define CHUNK 16
#define NCHUNK (NO / CHUNK)          // 128
#define LDSTR 132   // padded LDS row stride (floats): 2-way max conflicts + imm-offset ds_reads
#define LOG2E 1.4426950408889634f
#define NEG_BIG -3.0e38f
#define MASK_THRESH -1.0e37f
#define PART_STRIDE 136   // 4 m + 4 lsum + 128 acc (floats per (slot,q))
#define SY_MAX 32

// ---------------------------------------------------------------------------
// value path: h_obs <- LayerNorm(h_obs) @ Wv + bv (in place).
// ---------------------------------------------------------------------------
__global__ __launch_bounds__(256) void gano_value(
    const float* __restrict__ ln_g,
    const float* __restrict__ ln_b,
    const float* __restrict__ Wv,
    const float* __restrict__ bv,
    float* __restrict__ h)
{
    __shared__ float hn[LAT];
    __shared__ float red[8];
    __shared__ float part[LAT];
    const int t = threadIdx.x;
    const int o = blockIdx.x;
    const int d = t & 127;
    const int kh = t >> 7;

    const float x = h[(size_t)o*LAT + d];
    float s1 = x, s2 = x*x;
#pragma unroll
    for (int off = 32; off >= 1; off >>= 1) {
        s1 += __shfl_xor(s1, off);
        s2 += __shfl_xor(s2, off);
    }
    const int w = t >> 6;
    if ((t & 63) == 0) { red[w*2] = s1; red[w*2+1] = s2; }
    __syncthreads();
    const float S1 = red[0] + red[2];
    const float S2 = red[1] + red[3];
    const float mean = S1 * (1.0f/LAT);
    const float var  = S2 * (1.0f/LAT) - mean*mean;
    const float rstd = rsqrtf(var + 1e-5f);
    if (t < LAT)
        hn[d] = (x - mean) * rstd * ln_g[d] + ln_b[d];
    __syncthreads();

    float acc = kh ? 0.f : bv[d];
    const float* wp = Wv + (size_t)(kh*64)*LAT + d;
    const float* hp = hn + kh*64;
#pragma unroll 8
    for (int kk = 0; kk < 64; ++kk)
        acc = fmaf(hp[kk], wp[(size_t)kk*LAT], acc);
    if (kh) part[d] = acc;
    __syncthreads();
    if (!kh) h[(size_t)o*LAT + d] = acc + part[d];
}

// ---------------------------------------------------------------------------
// main, two-phase per chunk.
//  Phase 1: thread (qi,oc) computes the full 128-dim MLP logit for its own
//   (q,oc) pair. c_q / d_o tiles in LDS with PADDED stride 132 -> every read
//   is ds_read_b128 with an immediate offset (no per-j address VALU, deep
//   load bursts) at <=2-way banking. wd/W2 via loop-uniform s_loads.
//   Masked log2-domain logits -> lgt[q][h][oc'] (qi-rotated column).
//  Phase 2: thread (qi,i) owns dims [i*8,i*8+8); block-softmax over 4-oc
//   groups (one max/alpha/rescale per 4 obs: serial chain /4, VALU /1.6);
//   v read from global (L1-resident), 8x b128 per group.
// __launch_bounds__(256,7): 7 blocks/CU is the LDS-set residency; VGPR cap
// 72 gives the scheduler room to pipeline loads (watch FETCH for spill).
// ---------------------------------------------------------------------------
__global__ __launch_bounds__(256, 7) void gano_main(
    const float* __restrict__ v,          // h_obs buffer, now holding v
    const float* __restrict__ pos_obs,
    const float* __restrict__ pos_query,
    const int* __restrict__ obs_batch,
    const int* __restrict__ query_batch,
    const float* __restrict__ W1,
    const float* __restrict__ b1,
    const float* __restrict__ W2,
    const float* __restrict__ b2,
    float* __restrict__ ws,
    float* __restrict__ out,
    int SY)
{
    __shared__ __align__(16) float ld[CHUNK*LDSTR];   // d_o tile, padded   8.25 KB
    __shared__ __align__(16) float lcq[16*LDSTR];     // c_q, padded        8.25 KB
    __shared__ __align__(16) float lgt[16*4*CHUNK];   // logits [q][h][oc']    4 KB
    __shared__ float lpos[CHUNK*3];
    __shared__ int   lob[CHUNK];

    const int tid = threadIdx.x;
    const int i  = tid & 15;        // phase1: oc ; phase2: dim-slice
    const int qi = tid >> 4;        // query within block
    const int q  = blockIdx.x * 16 + qi;
    const int d0 = i * 8;           // phase-2 dims
    const int hstar = i >> 2;       // phase-2 head

    // ---- block-init: c_q into LDS (padded rows) ----
#pragma unroll
    for (int t2 = 0; t2 < 2; ++t2) {
        const int idx = tid + t2*256;
        const int row = idx >> 5;            // query 0..15
        const int g   = idx & 31;            // float4 group
        const int dd4 = g * 4;
        const int qq  = blockIdx.x * 16 + row;
        const float px = pos_query[qq*3+0];
        const float py = pos_query[qq*3+1];
        const float pz = pos_query[qq*3+2];
        float4 c = *(const float4*)(b1 + dd4);
        const float4 wx0 = *(const float4*)(W1 + 0*LAT + dd4);
        const float4 wx6 = *(const float4*)(W1 + 6*LAT + dd4);
        const float4 wy0 = *(const float4*)(W1 + 1*LAT + dd4);
        const float4 wy6 = *(const float4*)(W1 + 7*LAT + dd4);
        const float4 wz0 = *(const float4*)(W1 + 2*LAT + dd4);
        const float4 wz6 = *(const float4*)(W1 + 8*LAT + dd4);
        c.x = fmaf(px, wx0.x+wx6.x, fmaf(py, wy0.x+wy6.x, fmaf(pz, wz0.x+wz6.x, c.x)));
        c.y = fmaf(px, wx0.y+wx6.y, fmaf(py, wy0.y+wy6.y, fmaf(pz, wz0.y+wz6.y, c.y)));
        c.z = fmaf(px, wx0.z+wx6.z, fmaf(py, wy0.z+wy6.z, fmaf(pz, wz0.z+wz6.z, c.z)));
        c.w = fmaf(px, wx0.w+wx6.w, fmaf(py, wy0.w+wy6.w, fmaf(pz, wz0.w+wz6.w, c.w)));
        *(float4*)(lcq + row*LDSTR + dd4) = c;
    }

    const float pqx = pos_query[q*3+0];
    const float pqy = pos_query[q*3+1];
    const float pqz = pos_query[q*3+2];
    const int   qb  = query_batch[q];
    const float b2l0 = b2[0]*LOG2E, b2l1 = b2[1]*LOG2E;
    const float b2l2 = b2[2]*LOG2E, b2l3 = b2[3]*LOG2E;

    float4 accA = make_float4(0.f,0.f,0.f,0.f);
    float4 accB = make_float4(0.f,0.f,0.f,0.f);
    float m = NEG_BIG, lsum = 0.f;

    for (int cb = blockIdx.y; cb < NCHUNK; cb += SY) {
        const int o0 = cb * CHUNK;
        __syncthreads();   // prior phase-2 lgt reads done; lcq ready (1st)

        // ---- stage d_o (padded rows; W1 rows 3..8 straight from L1) ----
#pragma unroll
        for (int t2 = 0; t2 < 2; ++t2) {
            const int idx = tid + t2*256;
            const int oo = idx >> 5;           // obs within chunk
            const int g  = idx & 31;           // float4 group
            const int d4 = g * 4;
            const float* po = pos_obs + (size_t)(o0 + oo)*3;
            const float px = po[0], py = po[1], pz = po[2];
            const float4 w3 = *(const float4*)(W1 + 3*LAT + d4);
            const float4 w4 = *(const float4*)(W1 + 4*LAT + d4);
            const float4 w5 = *(const float4*)(W1 + 5*LAT + d4);
            const float4 w6 = *(const float4*)(W1 + 6*LAT + d4);
            const float4 w7 = *(const float4*)(W1 + 7*LAT + d4);
            const float4 w8 = *(const float4*)(W1 + 8*LAT + d4);
            float4 r;
            r.x = fmaf(px, w3.x-w6.x, fmaf(py, w4.x-w7.x, pz*(w5.x-w8.x)));
            r.y = fmaf(px, w3.y-w6.y, fmaf(py, w4.y-w7.y, pz*(w5.y-w8.y)));
            r.z = fmaf(px, w3.z-w6.z, fmaf(py, w4.z-w7.z, pz*(w5.z-w8.z)));
            r.w = fmaf(px, w3.w-w6.w, fmaf(py, w4.w-w7.w, pz*(w5.w-w8.w)));
            *(float4*)(ld + oo*LDSTR + d4) = r;
        }
        for (int idx = tid; idx < CHUNK*3; idx += 256) lpos[idx] = pos_obs[o0*3 + idx];
        for (int idx = tid; idx < CHUNK;   idx += 256) lob[idx]  = obs_batch[o0 + idx];
        __syncthreads();

        // ---- phase 1: one full logit per thread, no reduction ----
        {
            const int oc = i;
            const float dx = pqx - lpos[oc*3+0];
            const float dy = pqy - lpos[oc*3+1];
            const float dz = pqz - lpos[oc*3+2];
            const float dist = sqrtf(dx*dx + dy*dy + dz*dz);
            const int mb = (lob[oc] == qb);

            float lg0 = 0.f, lg1 = 0.f, lg2 = 0.f, lg3 = 0.f;
            const float* ldr = ld + oc*LDSTR;     // imm-offset reads from here
            const float* lcr = lcq + qi*LDSTR;
#pragma unroll 4
            for (int j = 0; j < 32; ++j) {
                const float4 dd = *(const float4*)(ldr + j*4);
                const float4 cc = *(const float4*)(lcr + j*4);
                const float4 wd = *(const float4*)(W1 + 9*LAT + j*4);   // uniform -> s_load
                const float4 w2a = *(const float4*)(W2 + (j*4+0)*4);    // uniform
                const float4 w2b = *(const float4*)(W2 + (j*4+1)*4);
                const float4 w2c = *(const float4*)(W2 + (j*4+2)*4);
                const float4 w2d = *(const float4*)(W2 + (j*4+3)*4);
                const float h0 = fmaxf(fmaf(wd.x, dist, cc.x + dd.x), 0.f);
                const float h1 = fmaxf(fmaf(wd.y, dist, cc.y + dd.y), 0.f);
                const float h2 = fmaxf(fmaf(wd.z, dist, cc.z + dd.z), 0.f);
                const float h3 = fmaxf(fmaf(wd.w, dist, cc.w + dd.w), 0.f);
                lg0 = fmaf(h0, w2a.x, lg0); lg1 = fmaf(h0, w2a.y, lg1);
                lg2 = fmaf(h0, w2a.z, lg2); lg3 = fmaf(h0, w2a.w, lg3);
                lg0 = fmaf(h1, w2b.x, lg0); lg1 = fmaf(h1, w2b.y, lg1);
                lg2 = fmaf(h1, w2b.z, lg2); lg3 = fmaf(h1, w2b.w, lg3);
                lg0 = fmaf(h2, w2c.x, lg0); lg1 = fmaf(h2, w2c.y, lg1);
                lg2 = fmaf(h2, w2c.z, lg2); lg3 = fmaf(h2, w2c.w, lg3);
                lg0 = fmaf(h3, w2d.x, lg0); lg1 = fmaf(h3, w2d.y, lg1);
                lg2 = fmaf(h3, w2d.z, lg2); lg3 = fmaf(h3, w2d.w, lg3);
            }
            // log2-domain, fold b2, apply mask; store qi-rotated column
            const int ocr = (oc + 4*qi) & 15;
            float* lrow = lgt + (qi*4)*CHUNK + ocr;
            lrow[0*CHUNK] = mb ? fmaf(lg0, LOG2E, b2l0) : NEG_BIG;
            lrow[1*CHUNK] = mb ? fmaf(lg1, LOG2E, b2l1) : NEG_BIG;
            lrow[2*CHUNK] = mb ? fmaf(lg2, LOG2E, b2l2) : NEG_BIG;
            lrow[3*CHUNK] = mb ? fmaf(lg3, LOG2E, b2l3) : NEG_BIG;
        }
        __syncthreads();

        // ---- phase 2: block-softmax over 4-oc groups + aggregation ----
        {
            const float* rowp = lgt + (qi*4 + hstar)*CHUNK;
            float lgv[16];
#pragma unroll
            for (int p = 0; p < 4; ++p) {
                const float4 t = *(const float4*)(rowp + ((p + qi) & 3) * 4);
                lgv[p*4+0] = t.x; lgv[p*4+1] = t.y;
                lgv[p*4+2] = t.z; lgv[p*4+3] = t.w;
            }
#pragma unroll
            for (int og = 0; og < 4; ++og) {
                const float l0 = lgv[og*4+0], l1 = lgv[og*4+1];
                const float l2 = lgv[og*4+2], l3 = lgv[og*4+3];
                const float mg = fmaxf(fmaxf(l0, l1), fmaxf(l2, l3));
                const float mn = fmaxf(m, mg);
                const float alpha = exp2f(m - mn);
                const float p0 = (l0 > MASK_THRESH) ? exp2f(l0 - mn) : 0.f;
                const float p1 = (l1 > MASK_THRESH) ? exp2f(l1 - mn) : 0.f;
                const float p2 = (l2 > MASK_THRESH) ? exp2f(l2 - mn) : 0.f;
                const float p3 = (l3 > MASK_THRESH) ? exp2f(l3 - mn) : 0.f;
                lsum = fmaf(lsum, alpha, (p0 + p1) + (p2 + p3));
                m = mn;

                const float* vp = v + (size_t)(o0 + og*4)*LAT + d0;
                const float4 v0A = *(const float4*)(vp + 0*LAT);
                const float4 v0B = *(const float4*)(vp + 0*LAT + 4);
                const float4 v1A = *(const float4*)(vp + 1*LAT);
                const float4 v1B = *(const float4*)(vp + 1*LAT + 4);
                const float4 v2A = *(const float4*)(vp + 2*LAT);
                const float4 v2B = *(const float4*)(vp + 2*LAT + 4);
                const float4 v3A = *(const float4*)(vp + 3*LAT);
                const float4 v3B = *(const float4*)(vp + 3*LAT + 4);
                accA.x = fmaf(accA.x, alpha, fmaf(p0, v0A.x, fmaf(p1, v1A.x, fmaf(p2, v2A.x, p3*v3A.x))));
                accA.y = fmaf(accA.y, alpha, fmaf(p0, v0A.y, fmaf(p1, v1A.y, fmaf(p2, v2A.y, p3*v3A.y))));
                accA.z = fmaf(accA.z, alpha, fmaf(p0, v0A.z, fmaf(p1, v1A.z, fmaf(p2, v2A.z, p3*v3A.z))));
                accA.w = fmaf(accA.w, alpha, fmaf(p0, v0A.w, fmaf(p1, v1A.w, fmaf(p2, v2A.w, p3*v3A.w))));
                accB.x = fmaf(accB.x, alpha, fmaf(p0, v0B.x, fmaf(p1, v1B.x, fmaf(p2, v2B.x, p3*v3B.x))));
                accB.y = fmaf(accB.y, alpha, fmaf(p0, v0B.y, fmaf(p1, v1B.y, fmaf(p2, v2B.y, p3*v3B.y))));
                accB.z = fmaf(accB.z, alpha, fmaf(p0, v0B.z, fmaf(p1, v1B.z, fmaf(p2, v2B.z, p3*v3B.z))));
                accB.w = fmaf(accB.w, alpha, fmaf(p0, v0B.w, fmaf(p1, v1B.w, fmaf(p2, v2B.w, p3*v3B.w))));
            }
        }
    }

    if (SY == 1) {
        const float inv = 1.0f / lsum;
        float* op = out + (size_t)q*LAT + d0;
        float4 rA, rB;
        rA.x = accA.x*inv; rA.y = accA.y*inv; rA.z = accA.z*inv; rA.w = accA.w*inv;
        rB.x = accB.x*inv; rB.y = accB.y*inv; rB.z = accB.z*inv; rB.w = accB.w*inv;
        *(float4*)op       = rA;
        *(float4*)(op + 4) = rB;
    } else {
        float* pp = ws + ((size_t)blockIdx.y * NQ + q) * PART_STRIDE;
        if ((i & 3) == 0) {          // one writer per head (redundant values identical)
            pp[hstar]     = m;
            pp[4 + hstar] = lsum;
        }
        *(float4*)(pp + 8 + d0)     = accA;
        *(float4*)(pp + 8 + d0 + 4) = accB;
    }
}

// ---------------------------------------------------------------------------
// combine: merge SY partials per query (log2-domain online merge), normalize
// ---------------------------------------------------------------------------
__global__ __launch_bounds__(128) void gano_combine(
    const float* __restrict__ ws, float* __restrict__ out, int SY)
{
    const int q = blockIdx.x;
    const int l = threadIdx.x;
    const int h = l >> 5;
    float M = NEG_BIG, Ls = 0.f, A = 0.f;
    for (int s = 0; s < SY; ++s) {
        const float* pp = ws + ((size_t)s * NQ + q) * PART_STRIDE;
        const float ms = pp[h];
        const float ls = pp[4 + h];
        const float as = pp[8 + l];
        const float Mn = fmaxf(M, ms);
        const float a0 = exp2f(M - Mn);
        const float a1 = exp2f(ms - Mn);
        Ls = Ls*a0 + ls*a1;
        A  = A *a0 + as*a1;
        M = Mn;
    }
    out[(size_t)q*LAT + l] = A / Ls;
}

// ---------------------------------------------------------------------------
extern "C" void kernel_launch(void* const* d_in, const int* in_sizes, int n_in,
                              void* d_out, int out_size, void* d_ws, size_t ws_size,
                              hipStream_t stream) {
    (void)in_sizes; (void)n_in; (void)out_size;
    float*       h_obs     = (float*)d_in[0];        // mutated in place -> v
    const float* pos_obs   = (const float*)d_in[1];
    const float* pos_query = (const float*)d_in[2];
    const int*   obs_batch = (const int*)d_in[3];
    const int*   query_batch = (const int*)d_in[4];
    const float* W1 = (const float*)d_in[5];
    const float* b1 = (const float*)d_in[6];
    const float* W2 = (const float*)d_in[7];
    const float* b2 = (const float*)d_in[8];
    const float* ln_g = (const float*)d_in[9];
    const float* ln_b = (const float*)d_in[10];
    const float* Wv = (const float*)d_in[11];
    const float* bv = (const float*)d_in[12];
    float* ws  = (float*)d_ws;
    float* out = (float*)d_out;

    // split-O factor: 32 -> grid 64x32 = 2048 blocks = 8/CU.
    // Strictly bounded by what d_ws can hold (0 bytes touched @ SY=1).
    int SY = 1;
    const size_t per = (size_t)NQ * PART_STRIDE * sizeof(float);
    if (ws && ws_size >= 2*per) {
        size_t s = ws_size / per;
        SY = (int)(s < SY_MAX ? s : SY_MAX);
    }

    gano_value<<<NO, 256, 0, stream>>>(ln_g, ln_b, Wv, bv, h_obs);
    gano_main<<<dim3(NQ/16, SY), 256, 0, stream>>>(h_obs, pos_obs, pos_query,
                                                   obs_batch, query_batch,
                                                   W1, b1, W2, b2, ws, out, SY);
    if (SY > 1)
        gano_combine<<<NQ, 128, 0, stream>>>(ws, out, SY);
}

// Round 8
// 200.216 us; speedup vs baseline: 3.2464x; 3.2464x over previous
//
#include <hip/hip_runtime.h>

#define NQ 1024
#define NO 2048
#define LAT 128
#define CHUNK 16
#define NCHUNK (NO / CHUNK)          // 128
#define LDSTR 132   // padded LDS row stride (floats): 2-way max conflicts + imm-offset ds_reads
#define LOG2E 1.4426950408889634f
#define NEG_BIG -3.0e38f
#define MASK_THRESH -1.0e37f
#define PART_STRIDE 136   // 4 m + 4 lsum + 128 acc (floats per (slot,q))
#define SY_MAX 32

// ---------------------------------------------------------------------------
// value path: h_obs <- LayerNorm(h_obs) @ Wv + bv (in place).
// ---------------------------------------------------------------------------
__global__ __launch_bounds__(256) void gano_value(
    const float* __restrict__ ln_g,
    const float* __restrict__ ln_b,
    const float* __restrict__ Wv,
    const float* __restrict__ bv,
    float* __restrict__ h)
{
    __shared__ float hn[LAT];
    __shared__ float red[8];
    __shared__ float part[LAT];
    const int t = threadIdx.x;
    const int o = blockIdx.x;
    const int d = t & 127;
    const int kh = t >> 7;

    const float x = h[(size_t)o*LAT + d];
    float s1 = x, s2 = x*x;
#pragma unroll
    for (int off = 32; off >= 1; off >>= 1) {
        s1 += __shfl_xor(s1, off);
        s2 += __shfl_xor(s2, off);
    }
    const int w = t >> 6;
    if ((t & 63) == 0) { red[w*2] = s1; red[w*2+1] = s2; }
    __syncthreads();
    const float S1 = red[0] + red[2];
    const float S2 = red[1] + red[3];
    const float mean = S1 * (1.0f/LAT);
    const float var  = S2 * (1.0f/LAT) - mean*mean;
    const float rstd = rsqrtf(var + 1e-5f);
    if (t < LAT)
        hn[d] = (x - mean) * rstd * ln_g[d] + ln_b[d];
    __syncthreads();

    float acc = kh ? 0.f : bv[d];
    const float* wp = Wv + (size_t)(kh*64)*LAT + d;
    const float* hp = hn + kh*64;
#pragma unroll 8
    for (int kk = 0; kk < 64; ++kk)
        acc = fmaf(hp[kk], wp[(size_t)kk*LAT], acc);
    if (kh) part[d] = acc;
    __syncthreads();
    if (!kh) h[(size_t)o*LAT + d] = acc + part[d];
}

// ---------------------------------------------------------------------------
// main, two-phase per chunk.
//  Phase 1: thread (qi,oc) computes the full 128-dim MLP logit for its own
//   (q,oc) pair. c_q / d_o tiles in LDS with PADDED stride 132 -> every read
//   is ds_read_b128 with an immediate offset (no per-j address VALU, deep
//   load bursts) at <=2-way banking. wd/W2 via loop-uniform s_loads.
//   Masked log2-domain logits -> lgt[q][h][oc'] (qi-rotated column).
//  Phase 2: thread (qi,i) owns dims [i*8,i*8+8); block-softmax over 4-oc
//   groups (one max/alpha/rescale per 4 obs); v from global (L1-resident),
//   8x b128 per group.
// __launch_bounds__(256) PLAIN — R7 lesson: the min-waves arg caps VGPRs at
// 256/w for 256-thread blocks; (256,7) capped at 36 and spilled 1.8 GB.
// Live set here ≈ 80 VGPRs; let the allocator choose.
// ---------------------------------------------------------------------------
__global__ __launch_bounds__(256) void gano_main(
    const float* __restrict__ v,          // h_obs buffer, now holding v
    const float* __restrict__ pos_obs,
    const float* __restrict__ pos_query,
    const int* __restrict__ obs_batch,
    const int* __restrict__ query_batch,
    const float* __restrict__ W1,
    const float* __restrict__ b1,
    const float* __restrict__ W2,
    const float* __restrict__ b2,
    float* __restrict__ ws,
    float* __restrict__ out,
    int SY)
{
    __shared__ __align__(16) float ld[CHUNK*LDSTR];   // d_o tile, padded   8.25 KB
    __shared__ __align__(16) float lcq[16*LDSTR];     // c_q, padded        8.25 KB
    __shared__ __align__(16) float lgt[16*4*CHUNK];   // logits [q][h][oc']    4 KB
    __shared__ float lpos[CHUNK*3];
    __shared__ int   lob[CHUNK];

    const int tid = threadIdx.x;
    const int i  = tid & 15;        // phase1: oc ; phase2: dim-slice
    const int qi = tid >> 4;        // query within block
    const int q  = blockIdx.x * 16 + qi;
    const int d0 = i * 8;           // phase-2 dims
    const int hstar = i >> 2;       // phase-2 head

    // ---- block-init: c_q into LDS (padded rows) ----
#pragma unroll
    for (int t2 = 0; t2 < 2; ++t2) {
        const int idx = tid + t2*256;
        const int row = idx >> 5;            // query 0..15
        const int g   = idx & 31;            // float4 group
        const int dd4 = g * 4;
        const int qq  = blockIdx.x * 16 + row;
        const float px = pos_query[qq*3+0];
        const float py = pos_query[qq*3+1];
        const float pz = pos_query[qq*3+2];
        float4 c = *(const float4*)(b1 + dd4);
        const float4 wx0 = *(const float4*)(W1 + 0*LAT + dd4);
        const float4 wx6 = *(const float4*)(W1 + 6*LAT + dd4);
        const float4 wy0 = *(const float4*)(W1 + 1*LAT + dd4);
        const float4 wy6 = *(const float4*)(W1 + 7*LAT + dd4);
        const float4 wz0 = *(const float4*)(W1 + 2*LAT + dd4);
        const float4 wz6 = *(const float4*)(W1 + 8*LAT + dd4);
        c.x = fmaf(px, wx0.x+wx6.x, fmaf(py, wy0.x+wy6.x, fmaf(pz, wz0.x+wz6.x, c.x)));
        c.y = fmaf(px, wx0.y+wx6.y, fmaf(py, wy0.y+wy6.y, fmaf(pz, wz0.y+wz6.y, c.y)));
        c.z = fmaf(px, wx0.z+wx6.z, fmaf(py, wy0.z+wy6.z, fmaf(pz, wz0.z+wz6.z, c.z)));
        c.w = fmaf(px, wx0.w+wx6.w, fmaf(py, wy0.w+wy6.w, fmaf(pz, wz0.w+wz6.w, c.w)));
        *(float4*)(lcq + row*LDSTR + dd4) = c;
    }

    const float pqx = pos_query[q*3+0];
    const float pqy = pos_query[q*3+1];
    const float pqz = pos_query[q*3+2];
    const int   qb  = query_batch[q];
    const float b2l0 = b2[0]*LOG2E, b2l1 = b2[1]*LOG2E;
    const float b2l2 = b2[2]*LOG2E, b2l3 = b2[3]*LOG2E;

    float4 accA = make_float4(0.f,0.f,0.f,0.f);
    float4 accB = make_float4(0.f,0.f,0.f,0.f);
    float m = NEG_BIG, lsum = 0.f;

    for (int cb = blockIdx.y; cb < NCHUNK; cb += SY) {
        const int o0 = cb * CHUNK;
        __syncthreads();   // prior phase-2 lgt reads done; lcq ready (1st)

        // ---- stage d_o (padded rows; W1 rows 3..8 straight from L1) ----
#pragma unroll
        for (int t2 = 0; t2 < 2; ++t2) {
            const int idx = tid + t2*256;
            const int oo = idx >> 5;           // obs within chunk
            const int g  = idx & 31;           // float4 group
            const int d4 = g * 4;
            const float* po = pos_obs + (size_t)(o0 + oo)*3;
            const float px = po[0], py = po[1], pz = po[2];
            const float4 w3 = *(const float4*)(W1 + 3*LAT + d4);
            const float4 w4 = *(const float4*)(W1 + 4*LAT + d4);
            const float4 w5 = *(const float4*)(W1 + 5*LAT + d4);
            const float4 w6 = *(const float4*)(W1 + 6*LAT + d4);
            const float4 w7 = *(const float4*)(W1 + 7*LAT + d4);
            const float4 w8 = *(const float4*)(W1 + 8*LAT + d4);
            float4 r;
            r.x = fmaf(px, w3.x-w6.x, fmaf(py, w4.x-w7.x, pz*(w5.x-w8.x)));
            r.y = fmaf(px, w3.y-w6.y, fmaf(py, w4.y-w7.y, pz*(w5.y-w8.y)));
            r.z = fmaf(px, w3.z-w6.z, fmaf(py, w4.z-w7.z, pz*(w5.z-w8.z)));
            r.w = fmaf(px, w3.w-w6.w, fmaf(py, w4.w-w7.w, pz*(w5.w-w8.w)));
            *(float4*)(ld + oo*LDSTR + d4) = r;
        }
        for (int idx = tid; idx < CHUNK*3; idx += 256) lpos[idx] = pos_obs[o0*3 + idx];
        for (int idx = tid; idx < CHUNK;   idx += 256) lob[idx]  = obs_batch[o0 + idx];
        __syncthreads();

        // ---- phase 1: one full logit per thread, no reduction ----
        {
            const int oc = i;
            const float dx = pqx - lpos[oc*3+0];
            const float dy = pqy - lpos[oc*3+1];
            const float dz = pqz - lpos[oc*3+2];
            const float dist = sqrtf(dx*dx + dy*dy + dz*dz);
            const int mb = (lob[oc] == qb);

            float lg0 = 0.f, lg1 = 0.f, lg2 = 0.f, lg3 = 0.f;
            const float* ldr = ld + oc*LDSTR;     // imm-offset reads from here
            const float* lcr = lcq + qi*LDSTR;
#pragma unroll 4
            for (int j = 0; j < 32; ++j) {
                const float4 dd = *(const float4*)(ldr + j*4);
                const float4 cc = *(const float4*)(lcr + j*4);
                const float4 wd = *(const float4*)(W1 + 9*LAT + j*4);   // uniform -> s_load
                const float4 w2a = *(const float4*)(W2 + (j*4+0)*4);    // uniform
                const float4 w2b = *(const float4*)(W2 + (j*4+1)*4);
                const float4 w2c = *(const float4*)(W2 + (j*4+2)*4);
                const float4 w2d = *(const float4*)(W2 + (j*4+3)*4);
                const float h0 = fmaxf(fmaf(wd.x, dist, cc.x + dd.x), 0.f);
                const float h1 = fmaxf(fmaf(wd.y, dist, cc.y + dd.y), 0.f);
                const float h2 = fmaxf(fmaf(wd.z, dist, cc.z + dd.z), 0.f);
                const float h3 = fmaxf(fmaf(wd.w, dist, cc.w + dd.w), 0.f);
                lg0 = fmaf(h0, w2a.x, lg0); lg1 = fmaf(h0, w2a.y, lg1);
                lg2 = fmaf(h0, w2a.z, lg2); lg3 = fmaf(h0, w2a.w, lg3);
                lg0 = fmaf(h1, w2b.x, lg0); lg1 = fmaf(h1, w2b.y, lg1);
                lg2 = fmaf(h1, w2b.z, lg2); lg3 = fmaf(h1, w2b.w, lg3);
                lg0 = fmaf(h2, w2c.x, lg0); lg1 = fmaf(h2, w2c.y, lg1);
                lg2 = fmaf(h2, w2c.z, lg2); lg3 = fmaf(h2, w2c.w, lg3);
                lg0 = fmaf(h3, w2d.x, lg0); lg1 = fmaf(h3, w2d.y, lg1);
                lg2 = fmaf(h3, w2d.z, lg2); lg3 = fmaf(h3, w2d.w, lg3);
            }
            // log2-domain, fold b2, apply mask; store qi-rotated column
            const int ocr = (oc + 4*qi) & 15;
            float* lrow = lgt + (qi*4)*CHUNK + ocr;
            lrow[0*CHUNK] = mb ? fmaf(lg0, LOG2E, b2l0) : NEG_BIG;
            lrow[1*CHUNK] = mb ? fmaf(lg1, LOG2E, b2l1) : NEG_BIG;
            lrow[2*CHUNK] = mb ? fmaf(lg2, LOG2E, b2l2) : NEG_BIG;
            lrow[3*CHUNK] = mb ? fmaf(lg3, LOG2E, b2l3) : NEG_BIG;
        }
        __syncthreads();

        // ---- phase 2: block-softmax over 4-oc groups + aggregation ----
        {
            const float* rowp = lgt + (qi*4 + hstar)*CHUNK;
            float lgv[16];
#pragma unroll
            for (int p = 0; p < 4; ++p) {
                const float4 t = *(const float4*)(rowp + ((p + qi) & 3) * 4);
                lgv[p*4+0] = t.x; lgv[p*4+1] = t.y;
                lgv[p*4+2] = t.z; lgv[p*4+3] = t.w;
            }
#pragma unroll
            for (int og = 0; og < 4; ++og) {
                const float l0 = lgv[og*4+0], l1 = lgv[og*4+1];
                const float l2 = lgv[og*4+2], l3 = lgv[og*4+3];
                const float mg = fmaxf(fmaxf(l0, l1), fmaxf(l2, l3));
                const float mn = fmaxf(m, mg);
                const float alpha = exp2f(m - mn);
                const float p0 = (l0 > MASK_THRESH) ? exp2f(l0 - mn) : 0.f;
                const float p1 = (l1 > MASK_THRESH) ? exp2f(l1 - mn) : 0.f;
                const float p2 = (l2 > MASK_THRESH) ? exp2f(l2 - mn) : 0.f;
                const float p3 = (l3 > MASK_THRESH) ? exp2f(l3 - mn) : 0.f;
                lsum = fmaf(lsum, alpha, (p0 + p1) + (p2 + p3));
                m = mn;

                const float* vp = v + (size_t)(o0 + og*4)*LAT + d0;
                const float4 v0A = *(const float4*)(vp + 0*LAT);
                const float4 v0B = *(const float4*)(vp + 0*LAT + 4);
                const float4 v1A = *(const float4*)(vp + 1*LAT);
                const float4 v1B = *(const float4*)(vp + 1*LAT + 4);
                const float4 v2A = *(const float4*)(vp + 2*LAT);
                const float4 v2B = *(const float4*)(vp + 2*LAT + 4);
                const float4 v3A = *(const float4*)(vp + 3*LAT);
                const float4 v3B = *(const float4*)(vp + 3*LAT + 4);
                accA.x = fmaf(accA.x, alpha, fmaf(p0, v0A.x, fmaf(p1, v1A.x, fmaf(p2, v2A.x, p3*v3A.x))));
                accA.y = fmaf(accA.y, alpha, fmaf(p0, v0A.y, fmaf(p1, v1A.y, fmaf(p2, v2A.y, p3*v3A.y))));
                accA.z = fmaf(accA.z, alpha, fmaf(p0, v0A.z, fmaf(p1, v1A.z, fmaf(p2, v2A.z, p3*v3A.z))));
                accA.w = fmaf(accA.w, alpha, fmaf(p0, v0A.w, fmaf(p1, v1A.w, fmaf(p2, v2A.w, p3*v3A.w))));
                accB.x = fmaf(accB.x, alpha, fmaf(p0, v0B.x, fmaf(p1, v1B.x, fmaf(p2, v2B.x, p3*v3B.x))));
                accB.y = fmaf(accB.y, alpha, fmaf(p0, v0B.y, fmaf(p1, v1B.y, fmaf(p2, v2B.y, p3*v3B.y))));
                accB.z = fmaf(accB.z, alpha, fmaf(p0, v0B.z, fmaf(p1, v1B.z, fmaf(p2, v2B.z, p3*v3B.z))));
                accB.w = fmaf(accB.w, alpha, fmaf(p0, v0B.w, fmaf(p1, v1B.w, fmaf(p2, v2B.w, p3*v3B.w))));
            }
        }
    }

    if (SY == 1) {
        const float inv = 1.0f / lsum;
        float* op = out + (size_t)q*LAT + d0;
        float4 rA, rB;
        rA.x = accA.x*inv; rA.y = accA.y*inv; rA.z = accA.z*inv; rA.w = accA.w*inv;
        rB.x = accB.x*inv; rB.y = accB.y*inv; rB.z = accB.z*inv; rB.w = accB.w*inv;
        *(float4*)op       = rA;
        *(float4*)(op + 4) = rB;
    } else {
        float* pp = ws + ((size_t)blockIdx.y * NQ + q) * PART_STRIDE;
        if ((i & 3) == 0) {          // one writer per head (redundant values identical)
            pp[hstar]     = m;
            pp[4 + hstar] = lsum;
        }
        *(float4*)(pp + 8 + d0)     = accA;
        *(float4*)(pp + 8 + d0 + 4) = accB;
    }
}

// ---------------------------------------------------------------------------
// combine: merge SY partials per query (log2-domain online merge), normalize
// ---------------------------------------------------------------------------
__global__ __launch_bounds__(128) void gano_combine(
    const float* __restrict__ ws, float* __restrict__ out, int SY)
{
    const int q = blockIdx.x;
    const int l = threadIdx.x;
    const int h = l >> 5;
    float M = NEG_BIG, Ls = 0.f, A = 0.f;
    for (int s = 0; s < SY; ++s) {
        const float* pp = ws + ((size_t)s * NQ + q) * PART_STRIDE;
        const float ms = pp[h];
        const float ls = pp[4 + h];
        const float as = pp[8 + l];
        const float Mn = fmaxf(M, ms);
        const float a0 = exp2f(M - Mn);
        const float a1 = exp2f(ms - Mn);
        Ls = Ls*a0 + ls*a1;
        A  = A *a0 + as*a1;
        M = Mn;
    }
    out[(size_t)q*LAT + l] = A / Ls;
}

// ---------------------------------------------------------------------------
extern "C" void kernel_launch(void* const* d_in, const int* in_sizes, int n_in,
                              void* d_out, int out_size, void* d_ws, size_t ws_size,
                              hipStream_t stream) {
    (void)in_sizes; (void)n_in; (void)out_size;
    float*       h_obs     = (float*)d_in[0];        // mutated in place -> v
    const float* pos_obs   = (const float*)d_in[1];
    const float* pos_query = (const float*)d_in[2];
    const int*   obs_batch = (const int*)d_in[3];
    const int*   query_batch = (const int*)d_in[4];
    const float* W1 = (const float*)d_in[5];
    const float* b1 = (const float*)d_in[6];
    const float* W2 = (const float*)d_in[7];
    const float* b2 = (const float*)d_in[8];
    const float* ln_g = (const float*)d_in[9];
    const float* ln_b = (const float*)d_in[10];
    const float* Wv = (const float*)d_in[11];
    const float* bv = (const float*)d_in[12];
    float* ws  = (float*)d_ws;
    float* out = (float*)d_out;

    // split-O factor: 32 -> grid 64x32 = 2048 blocks = 8/CU.
    // Strictly bounded by what d_ws can hold (0 bytes touched @ SY=1).
    int SY = 1;
    const size_t per = (size_t)NQ * PART_STRIDE * sizeof(float);
    if (ws && ws_size >= 2*per) {
        size_t s = ws_size / per;
        SY = (int)(s < SY_MAX ? s : SY_MAX);
    }

    gano_value<<<NO, 256, 0, stream>>>(ln_g, ln_b, Wv, bv, h_obs);
    gano_main<<<dim3(NQ/16, SY), 256, 0, stream>>>(h_obs, pos_obs, pos_query,
                                                   obs_batch, query_batch,
                                                   W1, b1, W2, b2, ws, out, SY);
    if (SY > 1)
        gano_combine<<<NQ, 128, 0, stream>>>(ws, out, SY);
}

// Round 9
// 191.573 us; speedup vs baseline: 3.3929x; 1.0451x over previous
//
#include <hip/hip_runtime.h>

#define NQ 1024
#define NO 2048
#define LAT 128
#define CHUNK 16
#define NCHUNK (NO / CHUNK)          // 128
#define LDSTR 132   // padded LDS row stride (floats)
#define LOG2E 1.4426950408889634f
#define NEG_BIG -3.0e38f
#define MASK_THRESH -1.0e37f
#define PART_STRIDE 136   // 4 m + 4 lsum + 128 acc (floats per (slot,q))
#define SY_MAX 32

// ---------------------------------------------------------------------------
// value path: h_obs <- LayerNorm(h_obs) @ Wv + bv (in place).
// 2 obs x 128 threads per block (1024 blocks); the 128-step k-chain is split
// into 4 accumulators (chain depth 32, ILP 4). All Wv loads coalesced and
// independent -> deep vmem pipelining. R8's version had a single 64-deep
// dependent chain at 8 blocks/CU and ate ~60 us.
// ---------------------------------------------------------------------------
__global__ __launch_bounds__(256) void gano_value(
    const float* __restrict__ ln_g,
    const float* __restrict__ ln_b,
    const float* __restrict__ Wv,
    const float* __restrict__ bv,
    float* __restrict__ h)
{
    __shared__ float hn[2][LAT];
    __shared__ float red[2][4];
    const int t = threadIdx.x;
    const int o = t >> 7;           // obs within block (0..1)
    const int d = t & 127;          // output dim
    const int ob = blockIdx.x * 2 + o;

    const float x = h[(size_t)ob*LAT + d];
    float s1 = x, s2 = x*x;
#pragma unroll
    for (int off = 32; off >= 1; off >>= 1) {
        s1 += __shfl_xor(s1, off);
        s2 += __shfl_xor(s2, off);
    }
    const int wv = (t >> 6) & 1;    // wave within obs
    if ((t & 63) == 0) { red[o][wv*2] = s1; red[o][wv*2+1] = s2; }
    __syncthreads();
    const float S1 = red[o][0] + red[o][2];
    const float S2 = red[o][1] + red[o][3];
    const float mean = S1 * (1.0f/LAT);
    const float var  = S2 * (1.0f/LAT) - mean*mean;
    const float rstd = rsqrtf(var + 1e-5f);
    hn[o][d] = (x - mean) * rstd * ln_g[d] + ln_b[d];
    __syncthreads();

    float a0 = bv[d], a1 = 0.f, a2 = 0.f, a3 = 0.f;
    const float* wc = Wv + d;
    const float* hh = hn[o];
#pragma unroll 8
    for (int kk = 0; kk < 32; ++kk) {
        a0 = fmaf(hh[kk],      wc[(size_t)(kk)*LAT],      a0);
        a1 = fmaf(hh[kk + 32], wc[(size_t)(kk + 32)*LAT], a1);
        a2 = fmaf(hh[kk + 64], wc[(size_t)(kk + 64)*LAT], a2);
        a3 = fmaf(hh[kk + 96], wc[(size_t)(kk + 96)*LAT], a3);
    }
    h[(size_t)ob*LAT + d] = (a0 + a1) + (a2 + a3);
}

// ---------------------------------------------------------------------------
// main, two-phase per chunk (structure as R8; phase-2 register diet).
//  Phase 1: thread (qi,oc) computes the full 128-dim MLP logit for its own
//   (q,oc) pair; padded-stride LDS tiles; W1[9]/W2 via uniform s_loads.
//  Phase 2: obs PAIRS (2 obs per softmax step): lgt float4 read per 4-obs
//   group, v loads only 2 obs in flight -> live set ~80 VGPR (R8's 4-obs
//   batch + lgv[16] preload hit 108 -> only 4 waves/SIMD).
// Plain __launch_bounds__(256): min-waves arg caps VGPR at 256/w (R7: 36 -> spill).
// ---------------------------------------------------------------------------
__global__ __launch_bounds__(256) void gano_main(
    const float* __restrict__ v,          // h_obs buffer, now holding v
    const float* __restrict__ pos_obs,
    const float* __restrict__ pos_query,
    const int* __restrict__ obs_batch,
    const int* __restrict__ query_batch,
    const float* __restrict__ W1,
    const float* __restrict__ b1,
    const float* __restrict__ W2,
    const float* __restrict__ b2,
    float* __restrict__ ws,
    float* __restrict__ out,
    int SY)
{
    __shared__ __align__(16) float ld[CHUNK*LDSTR];   // d_o tile, padded
    __shared__ __align__(16) float lcq[16*LDSTR];     // c_q, padded
    __shared__ __align__(16) float lgt[16*4*CHUNK];   // logits [q][h][oc']
    __shared__ float lpos[CHUNK*3];
    __shared__ int   lob[CHUNK];

    const int tid = threadIdx.x;
    const int i  = tid & 15;        // phase1: oc ; phase2: dim-slice
    const int qi = tid >> 4;        // query within block
    const int q  = blockIdx.x * 16 + qi;
    const int d0 = i * 8;           // phase-2 dims
    const int hstar = i >> 2;       // phase-2 head

    // ---- block-init: c_q into LDS (padded rows) ----
#pragma unroll
    for (int t2 = 0; t2 < 2; ++t2) {
        const int idx = tid + t2*256;
        const int row = idx >> 5;            // query 0..15
        const int g   = idx & 31;            // float4 group
        const int dd4 = g * 4;
        const int qq  = blockIdx.x * 16 + row;
        const float px = pos_query[qq*3+0];
        const float py = pos_query[qq*3+1];
        const float pz = pos_query[qq*3+2];
        float4 c = *(const float4*)(b1 + dd4);
        const float4 wx0 = *(const float4*)(W1 + 0*LAT + dd4);
        const float4 wx6 = *(const float4*)(W1 + 6*LAT + dd4);
        const float4 wy0 = *(const float4*)(W1 + 1*LAT + dd4);
        const float4 wy6 = *(const float4*)(W1 + 7*LAT + dd4);
        const float4 wz0 = *(const float4*)(W1 + 2*LAT + dd4);
        const float4 wz6 = *(const float4*)(W1 + 8*LAT + dd4);
        c.x = fmaf(px, wx0.x+wx6.x, fmaf(py, wy0.x+wy6.x, fmaf(pz, wz0.x+wz6.x, c.x)));
        c.y = fmaf(px, wx0.y+wx6.y, fmaf(py, wy0.y+wy6.y, fmaf(pz, wz0.y+wz6.y, c.y)));
        c.z = fmaf(px, wx0.z+wx6.z, fmaf(py, wy0.z+wy6.z, fmaf(pz, wz0.z+wz6.z, c.z)));
        c.w = fmaf(px, wx0.w+wx6.w, fmaf(py, wy0.w+wy6.w, fmaf(pz, wz0.w+wz6.w, c.w)));
        *(float4*)(lcq + row*LDSTR + dd4) = c;
    }

    const float pqx = pos_query[q*3+0];
    const float pqy = pos_query[q*3+1];
    const float pqz = pos_query[q*3+2];
    const int   qb  = query_batch[q];
    const float b2l0 = b2[0]*LOG2E, b2l1 = b2[1]*LOG2E;
    const float b2l2 = b2[2]*LOG2E, b2l3 = b2[3]*LOG2E;

    float4 accA = make_float4(0.f,0.f,0.f,0.f);
    float4 accB = make_float4(0.f,0.f,0.f,0.f);
    float m = NEG_BIG, lsum = 0.f;

    for (int cb = blockIdx.y; cb < NCHUNK; cb += SY) {
        const int o0 = cb * CHUNK;
        __syncthreads();   // prior phase-2 lgt reads done; lcq ready (1st)

        // ---- stage d_o (padded rows; W1 rows 3..8 straight from L1) ----
#pragma unroll
        for (int t2 = 0; t2 < 2; ++t2) {
            const int idx = tid + t2*256;
            const int oo = idx >> 5;           // obs within chunk
            const int g  = idx & 31;           // float4 group
            const int d4 = g * 4;
            const float* po = pos_obs + (size_t)(o0 + oo)*3;
            const float px = po[0], py = po[1], pz = po[2];
            const float4 w3 = *(const float4*)(W1 + 3*LAT + d4);
            const float4 w4 = *(const float4*)(W1 + 4*LAT + d4);
            const float4 w5 = *(const float4*)(W1 + 5*LAT + d4);
            const float4 w6 = *(const float4*)(W1 + 6*LAT + d4);
            const float4 w7 = *(const float4*)(W1 + 7*LAT + d4);
            const float4 w8 = *(const float4*)(W1 + 8*LAT + d4);
            float4 r;
            r.x = fmaf(px, w3.x-w6.x, fmaf(py, w4.x-w7.x, pz*(w5.x-w8.x)));
            r.y = fmaf(px, w3.y-w6.y, fmaf(py, w4.y-w7.y, pz*(w5.y-w8.y)));
            r.z = fmaf(px, w3.z-w6.z, fmaf(py, w4.z-w7.z, pz*(w5.z-w8.z)));
            r.w = fmaf(px, w3.w-w6.w, fmaf(py, w4.w-w7.w, pz*(w5.w-w8.w)));
            *(float4*)(ld + oo*LDSTR + d4) = r;
        }
        for (int idx = tid; idx < CHUNK*3; idx += 256) lpos[idx] = pos_obs[o0*3 + idx];
        for (int idx = tid; idx < CHUNK;   idx += 256) lob[idx]  = obs_batch[o0 + idx];
        __syncthreads();

        // ---- phase 1: one full logit per thread, no reduction ----
        {
            const int oc = i;
            const float dx = pqx - lpos[oc*3+0];
            const float dy = pqy - lpos[oc*3+1];
            const float dz = pqz - lpos[oc*3+2];
            const float dist = sqrtf(dx*dx + dy*dy + dz*dz);
            const int mb = (lob[oc] == qb);

            float lg0 = 0.f, lg1 = 0.f, lg2 = 0.f, lg3 = 0.f;
            const float* ldr = ld + oc*LDSTR;     // imm-offset reads from here
            const float* lcr = lcq + qi*LDSTR;
#pragma unroll 4
            for (int j = 0; j < 32; ++j) {
                const float4 dd = *(const float4*)(ldr + j*4);
                const float4 cc = *(const float4*)(lcr + j*4);
                const float4 wd = *(const float4*)(W1 + 9*LAT + j*4);   // uniform -> s_load
                const float4 w2a = *(const float4*)(W2 + (j*4+0)*4);    // uniform
                const float4 w2b = *(const float4*)(W2 + (j*4+1)*4);
                const float4 w2c = *(const float4*)(W2 + (j*4+2)*4);
                const float4 w2d = *(const float4*)(W2 + (j*4+3)*4);
                const float h0 = fmaxf(fmaf(wd.x, dist, cc.x + dd.x), 0.f);
                const float h1 = fmaxf(fmaf(wd.y, dist, cc.y + dd.y), 0.f);
                const float h2 = fmaxf(fmaf(wd.z, dist, cc.z + dd.z), 0.f);
                const float h3 = fmaxf(fmaf(wd.w, dist, cc.w + dd.w), 0.f);
                lg0 = fmaf(h0, w2a.x, lg0); lg1 = fmaf(h0, w2a.y, lg1);
                lg2 = fmaf(h0, w2a.z, lg2); lg3 = fmaf(h0, w2a.w, lg3);
                lg0 = fmaf(h1, w2b.x, lg0); lg1 = fmaf(h1, w2b.y, lg1);
                lg2 = fmaf(h1, w2b.z, lg2); lg3 = fmaf(h1, w2b.w, lg3);
                lg0 = fmaf(h2, w2c.x, lg0); lg1 = fmaf(h2, w2c.y, lg1);
                lg2 = fmaf(h2, w2c.z, lg2); lg3 = fmaf(h2, w2c.w, lg3);
                lg0 = fmaf(h3, w2d.x, lg0); lg1 = fmaf(h3, w2d.y, lg1);
                lg2 = fmaf(h3, w2d.z, lg2); lg3 = fmaf(h3, w2d.w, lg3);
            }
            // log2-domain, fold b2, apply mask; store qi-rotated column
            const int ocr = (oc + 4*qi) & 15;
            float* lrow = lgt + (qi*4)*CHUNK + ocr;
            lrow[0*CHUNK] = mb ? fmaf(lg0, LOG2E, b2l0) : NEG_BIG;
            lrow[1*CHUNK] = mb ? fmaf(lg1, LOG2E, b2l1) : NEG_BIG;
            lrow[2*CHUNK] = mb ? fmaf(lg2, LOG2E, b2l2) : NEG_BIG;
            lrow[3*CHUNK] = mb ? fmaf(lg3, LOG2E, b2l3) : NEG_BIG;
        }
        __syncthreads();

        // ---- phase 2: softmax over obs pairs + aggregation ----
        {
            const float* rowp = lgt + (qi*4 + hstar)*CHUNK;
#pragma unroll
            for (int og = 0; og < 4; ++og) {
                // float4 = logits of obs og*4..og*4+3 (rotation preserves groups)
                const float4 t4 = *(const float4*)(rowp + ((og + qi) & 3) * 4);
#pragma unroll
                for (int pr = 0; pr < 2; ++pr) {
                    const float l0 = pr ? t4.z : t4.x;
                    const float l1 = pr ? t4.w : t4.y;
                    const float mn = fmaxf(m, fmaxf(l0, l1));
                    const float alpha = exp2f(m - mn);
                    const float p0 = (l0 > MASK_THRESH) ? exp2f(l0 - mn) : 0.f;
                    const float p1 = (l1 > MASK_THRESH) ? exp2f(l1 - mn) : 0.f;
                    lsum = fmaf(lsum, alpha, p0 + p1);
                    m = mn;

                    const float* vp = v + (size_t)(o0 + og*4 + pr*2)*LAT + d0;
                    const float4 v0A = *(const float4*)(vp);
                    const float4 v0B = *(const float4*)(vp + 4);
                    const float4 v1A = *(const float4*)(vp + LAT);
                    const float4 v1B = *(const float4*)(vp + LAT + 4);
                    accA.x = fmaf(accA.x, alpha, fmaf(p0, v0A.x, p1*v1A.x));
                    accA.y = fmaf(accA.y, alpha, fmaf(p0, v0A.y, p1*v1A.y));
                    accA.z = fmaf(accA.z, alpha, fmaf(p0, v0A.z, p1*v1A.z));
                    accA.w = fmaf(accA.w, alpha, fmaf(p0, v0A.w, p1*v1A.w));
                    accB.x = fmaf(accB.x, alpha, fmaf(p0, v0B.x, p1*v1B.x));
                    accB.y = fmaf(accB.y, alpha, fmaf(p0, v0B.y, p1*v1B.y));
                    accB.z = fmaf(accB.z, alpha, fmaf(p0, v0B.z, p1*v1B.z));
                    accB.w = fmaf(accB.w, alpha, fmaf(p0, v0B.w, p1*v1B.w));
                }
            }
        }
    }

    if (SY == 1) {
        const float inv = 1.0f / lsum;
        float* op = out + (size_t)q*LAT + d0;
        float4 rA, rB;
        rA.x = accA.x*inv; rA.y = accA.y*inv; rA.z = accA.z*inv; rA.w = accA.w*inv;
        rB.x = accB.x*inv; rB.y = accB.y*inv; rB.z = accB.z*inv; rB.w = accB.w*inv;
        *(float4*)op       = rA;
        *(float4*)(op + 4) = rB;
    } else {
        float* pp = ws + ((size_t)blockIdx.y * NQ + q) * PART_STRIDE;
        if ((i & 3) == 0) {          // one writer per head (redundant values identical)
            pp[hstar]     = m;
            pp[4 + hstar] = lsum;
        }
        *(float4*)(pp + 8 + d0)     = accA;
        *(float4*)(pp + 8 + d0 + 4) = accB;
    }
}

// ---------------------------------------------------------------------------
// combine: two-phase merge (R8's 32 serially-DEPENDENT scattered loads ->
// stage m/lsum in LDS, compute M, then all per-slot loads are independent
// and pipeline; 2 accumulators).
// ---------------------------------------------------------------------------
__global__ __launch_bounds__(128) void gano_combine(
    const float* __restrict__ ws, float* __restrict__ out, int SY)
{
    __shared__ float lm[SY_MAX*4];
    __shared__ float ll[SY_MAX*4];
    const int q = blockIdx.x;
    const int l = threadIdx.x;
    const int h = l >> 5;

    if (l < SY*4) {
        const int s = l >> 2, hh = l & 3;
        const float* pp = ws + ((size_t)s * NQ + q) * PART_STRIDE;
        lm[l] = pp[hh];
        ll[l] = pp[4 + hh];
    }
    __syncthreads();

    float M = NEG_BIG;
    for (int s = 0; s < SY; ++s) M = fmaxf(M, lm[s*4 + h]);

    float Ls = 0.f, A0 = 0.f, A1 = 0.f;
#pragma unroll 4
    for (int s = 0; s + 1 < SY; s += 2) {
        const float e0 = exp2f(lm[s*4 + h] - M);
        const float e1 = exp2f(lm[(s+1)*4 + h] - M);
        Ls = fmaf(ll[s*4 + h], e0, fmaf(ll[(s+1)*4 + h], e1, Ls));
        A0 = fmaf(ws[((size_t)s     * NQ + q) * PART_STRIDE + 8 + l], e0, A0);
        A1 = fmaf(ws[((size_t)(s+1) * NQ + q) * PART_STRIDE + 8 + l], e1, A1);
    }
    if (SY & 1) {
        const int s = SY - 1;
        const float e0 = exp2f(lm[s*4 + h] - M);
        Ls = fmaf(ll[s*4 + h], e0, Ls);
        A0 = fmaf(ws[((size_t)s * NQ + q) * PART_STRIDE + 8 + l], e0, A0);
    }
    out[(size_t)q*LAT + l] = (A0 + A1) / Ls;
}

// ---------------------------------------------------------------------------
extern "C" void kernel_launch(void* const* d_in, const int* in_sizes, int n_in,
                              void* d_out, int out_size, void* d_ws, size_t ws_size,
                              hipStream_t stream) {
    (void)in_sizes; (void)n_in; (void)out_size;
    float*       h_obs     = (float*)d_in[0];        // mutated in place -> v
    const float* pos_obs   = (const float*)d_in[1];
    const float* pos_query = (const float*)d_in[2];
    const int*   obs_batch = (const int*)d_in[3];
    const int*   query_batch = (const int*)d_in[4];
    const float* W1 = (const float*)d_in[5];
    const float* b1 = (const float*)d_in[6];
    const float* W2 = (const float*)d_in[7];
    const float* b2 = (const float*)d_in[8];
    const float* ln_g = (const float*)d_in[9];
    const float* ln_b = (const float*)d_in[10];
    const float* Wv = (const float*)d_in[11];
    const float* bv = (const float*)d_in[12];
    float* ws  = (float*)d_ws;
    float* out = (float*)d_out;

    // split-O factor: 32 -> grid 64x32 = 2048 blocks = 8/CU.
    // Strictly bounded by what d_ws can hold (0 bytes touched @ SY=1).
    int SY = 1;
    const size_t per = (size_t)NQ * PART_STRIDE * sizeof(float);
    if (ws && ws_size >= 2*per) {
        size_t s = ws_size / per;
        SY = (int)(s < SY_MAX ? s : SY_MAX);
    }

    gano_value<<<NO/2, 256, 0, stream>>>(ln_g, ln_b, Wv, bv, h_obs);
    gano_main<<<dim3(NQ/16, SY), 256, 0, stream>>>(h_obs, pos_obs, pos_query,
                                                   obs_batch, query_batch,
                                                   W1, b1, W2, b2, ws, out, SY);
    if (SY > 1)
        gano_combine<<<NQ, 128, 0, stream>>>(ws, out, SY);
}